// Round 1
// baseline (1883.649 us; speedup 1.0000x reference)
//
#include <hip/hip_runtime.h>
#include <hip/hip_bf16.h>

#define N_NODES 100000
#define N_EDGES 3200000
#define N_GRAPHS 125
#define D 64

// degree: one thread per edge, atomic add 1.0 to deg[dst]
__global__ void deg_kernel(const int* __restrict__ dst, float* __restrict__ deg) {
    int i = blockIdx.x * blockDim.x + threadIdx.x;
    int stride = gridDim.x * blockDim.x;
    for (; i < N_EDGES; i += stride)
        atomicAdd(&deg[dst[i]], 1.0f);
}

// deg -> rsqrt(deg+1) in place
__global__ void dis_kernel(float* __restrict__ deg) {
    int i = blockIdx.x * blockDim.x + threadIdx.x;
    if (i < N_NODES) deg[i] = rsqrtf(deg[i] + 1.0f);
}

// Y[r][c] = sum_k X[r][k] * W[k][c] (+ bias[c] if bias != nullptr)
// block = 256 threads -> 4 rows x 64 cols
__global__ void gemm_kernel(const float* __restrict__ X, const float* __restrict__ W,
                            const float* __restrict__ bias, float* __restrict__ Y) {
    __shared__ float Ws[64][64];
    for (int i = threadIdx.x; i < 64 * 64; i += 256)
        Ws[i >> 6][i & 63] = W[i];
    __syncthreads();
    int c  = threadIdx.x & 63;
    int rl = threadIdx.x >> 6;  // 0..3
    int r  = blockIdx.x * 4 + rl;
    if (r < N_NODES) {
        const float* xr = X + (size_t)r * D;
        float acc = bias ? bias[c] : 0.0f;
#pragma unroll
        for (int k = 0; k < 64; ++k)
            acc = fmaf(xr[k], Ws[k][c], acc);
        Y[(size_t)r * D + c] = acc;
    }
}

// one wave (64 lanes) per edge, lane d handles feature dim d
__global__ void scatter_kernel(const float* __restrict__ H, const int* __restrict__ src,
                               const int* __restrict__ dst, const float* __restrict__ dis,
                               float* __restrict__ B) {
    int lane  = threadIdx.x & 63;
    int wave  = (blockIdx.x * blockDim.x + threadIdx.x) >> 6;
    int nwave = (gridDim.x * blockDim.x) >> 6;
    for (int e = wave; e < N_EDGES; e += nwave) {
        int s = src[e];
        int d = dst[e];
        float norm = dis[s] * dis[d];
        float v = H[(size_t)s * D + lane] * norm;
        atomicAdd(&B[(size_t)d * D + lane], v);
    }
}

// B = relu? (B + H*dis^2 + bias)
__global__ void finalize_kernel(const float* __restrict__ H, const float* __restrict__ dis,
                                const float* __restrict__ bias, float* __restrict__ B,
                                int do_relu) {
    int idx = blockIdx.x * blockDim.x + threadIdx.x;
    int total = N_NODES * D;
    int stride = gridDim.x * blockDim.x;
    for (; idx < total; idx += stride) {
        int r = idx >> 6;
        int c = idx & 63;
        float di = dis[r];
        float v = B[idx] + H[idx] * di * di + bias[c];
        if (do_relu) v = fmaxf(v, 0.0f);
        B[idx] = v;
    }
}

// one block per graph: mean over contiguous node segment [ptr[g], ptr[g+1])
__global__ void pool_kernel(const float* __restrict__ H, const int* __restrict__ ptr,
                            float* __restrict__ out) {
    int g = blockIdx.x;
    int start = ptr[g], end = ptr[g + 1];
    int lane  = threadIdx.x & 63;
    int chunk = threadIdx.x >> 6;  // 0..3
    float acc = 0.0f;
    for (int r = start + chunk; r < end; r += 4)
        acc += H[(size_t)r * D + lane];
    __shared__ float tmp[4][64];
    tmp[chunk][lane] = acc;
    __syncthreads();
    if (threadIdx.x < 64) {
        float s = tmp[0][lane] + tmp[1][lane] + tmp[2][lane] + tmp[3][lane];
        out[g * D + lane] = s / (float)(end - start);
    }
}

extern "C" void kernel_launch(void* const* d_in, const int* in_sizes, int n_in,
                              void* d_out, int out_size, void* d_ws, size_t ws_size,
                              hipStream_t stream) {
    const float* x   = (const float*)d_in[0];
    const int*   ei  = (const int*)d_in[1];
    const int*   src = ei;
    const int*   dst = ei + N_EDGES;
    const int*   ptr = (const int*)d_in[2];
    const float* W1  = (const float*)d_in[3];
    const float* b1  = (const float*)d_in[4];
    const float* W2  = (const float*)d_in[5];
    const float* b2  = (const float*)d_in[6];
    const float* Wf  = (const float*)d_in[7];
    const float* bfp = (const float*)d_in[8];
    float* out = (float*)d_out;

    // workspace layout (f32): dis[100352 aligned] | A[N*64] | B[N*64]
    float* dis = (float*)d_ws;
    float* A   = dis + 100352;          // 512B-aligned past 100000
    float* B   = A + (size_t)N_NODES * D;

    // zero dis and agg buffer B
    hipMemsetAsync(dis, 0, (size_t)N_NODES * sizeof(float), stream);
    hipMemsetAsync(B, 0, (size_t)N_NODES * D * sizeof(float), stream);

    // degree + rsqrt
    deg_kernel<<<2048, 256, 0, stream>>>(dst, dis);
    dis_kernel<<<(N_NODES + 255) / 256, 256, 0, stream>>>(dis);

    // layer 1: A = x @ W1 ; B = scatter(A) ; B = relu(B + A*dis^2 + b1)
    gemm_kernel<<<(N_NODES + 3) / 4, 256, 0, stream>>>(x, W1, nullptr, A);
    scatter_kernel<<<8192, 256, 0, stream>>>(A, src, dst, dis, B);
    finalize_kernel<<<8192, 256, 0, stream>>>(A, dis, b1, B, 1);

    // layer 2: A = B @ W2 ; zero B ; B = scatter(A) ; B = relu(B + A*dis^2 + b2)
    gemm_kernel<<<(N_NODES + 3) / 4, 256, 0, stream>>>(B, W2, nullptr, A);
    hipMemsetAsync(B, 0, (size_t)N_NODES * D * sizeof(float), stream);
    scatter_kernel<<<8192, 256, 0, stream>>>(A, src, dst, dis, B);
    finalize_kernel<<<8192, 256, 0, stream>>>(A, dis, b2, B, 1);

    // head: A = B @ Wf + bf ; pool
    gemm_kernel<<<(N_NODES + 3) / 4, 256, 0, stream>>>(B, Wf, bfp, A);
    pool_kernel<<<N_GRAPHS, 256, 0, stream>>>(A, ptr, out);
}

// Round 2
// 1103.201 us; speedup vs baseline: 1.7074x; 1.7074x over previous
//
#include <hip/hip_runtime.h>
#include <hip/hip_bf16.h>

#define N_NODES 100000
#define N_EDGES 3200000
#define N_GRAPHS 125
#define D 64
#define SCAN_BLK 1000   // nodes per scan block; 100 blocks x 1000 = 100000 exactly

// ---------- CSR build ----------

// histogram of dst -> cnt (in-degree, excluding self-loop)
__global__ void hist_kernel(const int* __restrict__ dst, int* __restrict__ cnt) {
    int i = blockIdx.x * blockDim.x + threadIdx.x;
    int stride = gridDim.x * blockDim.x;
    for (; i < N_EDGES; i += stride)
        atomicAdd(&cnt[dst[i]], 1);
}

// dis[i] = rsqrt(cnt[i] + 1)
__global__ void dis_kernel(const int* __restrict__ cnt, float* __restrict__ dis) {
    int i = blockIdx.x * blockDim.x + threadIdx.x;
    if (i < N_NODES) dis[i] = rsqrtf((float)cnt[i] + 1.0f);
}

// per-block sums of cnt (block b covers nodes [b*1000, b*1000+1000))
__global__ void scan1_kernel(const int* __restrict__ cnt, int* __restrict__ sums) {
    __shared__ int lds[256];
    int b = blockIdx.x, t = threadIdx.x;
    int base = b * SCAN_BLK;
    int s = 0;
    if (t < 250) {
#pragma unroll
        for (int k = 0; k < 4; ++k) s += cnt[base + t * 4 + k];
    }
    lds[t] = s;
    __syncthreads();
    for (int off = 128; off > 0; off >>= 1) {
        if (t < off) lds[t] += lds[t + off];
        __syncthreads();
    }
    if (t == 0) sums[b] = lds[0];
}

// exclusive scan of 100 block sums -> offs; also seal row_start[N]
__global__ void scan2_kernel(const int* __restrict__ sums, int* __restrict__ offs,
                             int* __restrict__ row_start) {
    __shared__ int lds[128];
    int t = threadIdx.x;  // 128 threads
    int own = (t < 100) ? sums[t] : 0;
    lds[t] = own;
    __syncthreads();
    for (int off = 1; off < 128; off <<= 1) {
        int v = (t >= off) ? lds[t - off] : 0;
        __syncthreads();
        lds[t] += v;
        __syncthreads();
    }
    if (t < 100) offs[t] = lds[t] - own;  // exclusive
    if (t == 0) row_start[N_NODES] = N_EDGES;
}

// within-block exclusive scan -> row_start + cursor
__global__ void scan3_kernel(const int* __restrict__ cnt, const int* __restrict__ offs,
                             int* __restrict__ row_start, int* __restrict__ cursor) {
    __shared__ int lds[256];
    int b = blockIdx.x, t = threadIdx.x;
    int base = b * SCAN_BLK;
    int local[4];
    int s = 0;
    if (t < 250) {
#pragma unroll
        for (int k = 0; k < 4; ++k) { local[k] = cnt[base + t * 4 + k]; s += local[k]; }
    }
    lds[t] = s;
    __syncthreads();
    for (int off = 1; off < 256; off <<= 1) {
        int v = (t >= off) ? lds[t - off] : 0;
        __syncthreads();
        lds[t] += v;
        __syncthreads();
    }
    if (t < 250) {
        int pre = lds[t] - s + offs[b];  // exclusive prefix within block + block offset
#pragma unroll
        for (int k = 0; k < 4; ++k) {
            int node = base + t * 4 + k;
            row_start[node] = pre;
            cursor[node] = pre;
            pre += local[k];
        }
    }
}

// scatter edges into CSR slots
__global__ void fill_kernel(const int* __restrict__ src, const int* __restrict__ dst,
                            int* __restrict__ cursor, int* __restrict__ csr) {
    int i = blockIdx.x * blockDim.x + threadIdx.x;
    int stride = gridDim.x * blockDim.x;
    for (; i < N_EDGES; i += stride) {
        int d = dst[i];
        int pos = atomicAdd(&cursor[d], 1);
        csr[pos] = src[i];
    }
}

// ---------- compute ----------

// Y[r][c] = sum_k X[r][k] * W[k][c] (+ bias[c] if bias != nullptr)
__global__ void gemm_kernel(const float* __restrict__ X, const float* __restrict__ W,
                            const float* __restrict__ bias, float* __restrict__ Y) {
    __shared__ float Ws[64][64];
    for (int i = threadIdx.x; i < 64 * 64; i += 256)
        Ws[i >> 6][i & 63] = W[i];
    __syncthreads();
    int c  = threadIdx.x & 63;
    int rl = threadIdx.x >> 6;  // 0..3
    int r  = blockIdx.x * 4 + rl;
    if (r < N_NODES) {
        const float* xr = X + (size_t)r * D;
        float acc = bias ? bias[c] : 0.0f;
#pragma unroll
        for (int k = 0; k < 64; ++k)
            acc = fmaf(xr[k], Ws[k][c], acc);
        Y[(size_t)r * D + c] = acc;
    }
}

// one wave per dst node: gather in-edges, fuse self-loop + bias + relu
__global__ void gather_kernel(const float* __restrict__ H, const int* __restrict__ csr,
                              const int* __restrict__ row_start, const float* __restrict__ dis,
                              const float* __restrict__ bias, float* __restrict__ Bout,
                              int do_relu) {
    int v = (blockIdx.x * blockDim.x + threadIdx.x) >> 6;
    int lane = threadIdx.x & 63;
    if (v >= N_NODES) return;
    int base = row_start[v];
    int n = row_start[v + 1] - base;
    float disv = dis[v];
    // self-loop (norm = disv^2) + bias
    float acc = fmaf(H[(size_t)v * D + lane], disv * disv, bias[lane]);
    for (int c = 0; c < n; c += 64) {
        int m = min(64, n - c);
        int sl = 0; float dl = 0.0f;
        if (lane < m) { sl = csr[base + c + lane]; dl = dis[sl]; }
        for (int j = 0; j < m; ++j) {
            int s = __shfl(sl, j);
            float nrm = __shfl(dl, j) * disv;
            acc = fmaf(H[(size_t)s * D + lane], nrm, acc);
        }
    }
    if (do_relu) acc = fmaxf(acc, 0.0f);
    Bout[(size_t)v * D + lane] = acc;
}

// one block per graph: mean over contiguous node segment [ptr[g], ptr[g+1])
__global__ void pool_kernel(const float* __restrict__ H, const int* __restrict__ ptr,
                            float* __restrict__ out) {
    int g = blockIdx.x;
    int start = ptr[g], end = ptr[g + 1];
    int lane  = threadIdx.x & 63;
    int chunk = threadIdx.x >> 6;  // 0..3
    float acc = 0.0f;
    for (int r = start + chunk; r < end; r += 4)
        acc += H[(size_t)r * D + lane];
    __shared__ float tmp[4][64];
    tmp[chunk][lane] = acc;
    __syncthreads();
    if (threadIdx.x < 64) {
        float s = tmp[0][lane] + tmp[1][lane] + tmp[2][lane] + tmp[3][lane];
        out[g * D + lane] = s / (float)(end - start);
    }
}

extern "C" void kernel_launch(void* const* d_in, const int* in_sizes, int n_in,
                              void* d_out, int out_size, void* d_ws, size_t ws_size,
                              hipStream_t stream) {
    const float* x   = (const float*)d_in[0];
    const int*   ei  = (const int*)d_in[1];
    const int*   src = ei;
    const int*   dst = ei + N_EDGES;
    const int*   ptr = (const int*)d_in[2];
    const float* W1  = (const float*)d_in[3];
    const float* b1  = (const float*)d_in[4];
    const float* W2  = (const float*)d_in[5];
    const float* b2  = (const float*)d_in[6];
    const float* Wf  = (const float*)d_in[7];
    const float* bfp = (const float*)d_in[8];
    float* out = (float*)d_out;

    // workspace layout (4-byte elems)
    int*   cnt       = (int*)d_ws;                 // 100352
    int*   row_start = cnt + 100352;               // 100352 (uses N_NODES+1)
    int*   cursor    = row_start + 100352;         // 100352
    int*   sums      = cursor + 100352;            // 128
    int*   offs      = sums + 128;                 // 128
    float* dis       = (float*)(offs + 128);       // 100352
    int*   csr       = (int*)(dis + 100352);       // 3200000
    float* A         = (float*)(csr + 3200000);    // 6400000
    float* B         = A + (size_t)N_NODES * D;    // 6400000

    // --- CSR build (once, reused by both layers) ---
    hipMemsetAsync(cnt, 0, (size_t)N_NODES * sizeof(int), stream);
    hist_kernel<<<2048, 256, 0, stream>>>(dst, cnt);
    dis_kernel<<<(N_NODES + 255) / 256, 256, 0, stream>>>(cnt, dis);
    scan1_kernel<<<100, 256, 0, stream>>>(cnt, sums);
    scan2_kernel<<<1, 128, 0, stream>>>(sums, offs, row_start);
    scan3_kernel<<<100, 256, 0, stream>>>(cnt, offs, row_start, cursor);
    fill_kernel<<<2048, 256, 0, stream>>>(src, dst, cursor, csr);

    const int gemm_grid = (N_NODES + 3) / 4;
    const int gather_grid = (N_NODES + 3) / 4;  // 4 waves (nodes) per 256-thread block

    // layer 1: A = x @ W1 ; B = relu(gather(A) + A*dis^2 + b1)
    gemm_kernel<<<gemm_grid, 256, 0, stream>>>(x, W1, nullptr, A);
    gather_kernel<<<gather_grid, 256, 0, stream>>>(A, csr, row_start, dis, b1, B, 1);

    // layer 2
    gemm_kernel<<<gemm_grid, 256, 0, stream>>>(B, W2, nullptr, A);
    gather_kernel<<<gather_grid, 256, 0, stream>>>(A, csr, row_start, dis, b2, B, 1);

    // head + pool
    gemm_kernel<<<gemm_grid, 256, 0, stream>>>(B, Wf, bfp, A);
    pool_kernel<<<N_GRAPHS, 256, 0, stream>>>(A, ptr, out);
}

// Round 3
// 730.297 us; speedup vs baseline: 2.5793x; 1.5106x over previous
//
#include <hip/hip_runtime.h>
#include <hip/hip_bf16.h>

#define N_NODES 100000
#define N_EDGES 3200000
#define N_GRAPHS 125
#define D 64
#define NB 200          // buckets
#define BW 500          // nodes per bucket (NB*BW == N_NODES)
#define CAP 20480       // max edges per bucket (mean 16000, sigma ~126)
#define EPW 16000       // edges per workgroup in bucket_scatter (NB wgs)

// ---------- CSR build (bucketed, LDS-atomic) ----------

__global__ void init_bcursor(int* __restrict__ bcursor) {
    int t = blockIdx.x * blockDim.x + threadIdx.x;
    if (t < NB) bcursor[t] = t * CAP;
}

// partition edges into NB dst-range buckets; writes (src,dst) pairs densely
__global__ void bucket_scatter(const int* __restrict__ src, const int* __restrict__ dst,
                               int* __restrict__ bcursor, int2* __restrict__ pairs) {
    __shared__ int bins[NB];
    int wg = blockIdx.x, t = threadIdx.x;
    int e0 = wg * EPW, e1 = e0 + EPW;
    if (t < NB) bins[t] = 0;
    __syncthreads();
    // phase A: count
    for (int i = e0 + t; i < e1; i += 256)
        atomicAdd(&bins[dst[i] / BW], 1);
    __syncthreads();
    // phase B: reserve global space; bins becomes absolute cursor
    if (t < NB) {
        int c = bins[t];
        bins[t] = c ? atomicAdd(&bcursor[t], c) : 0;
    }
    __syncthreads();
    // phase C: write pairs
    for (int i = e0 + t; i < e1; i += 256) {
        int s = src[i], d = dst[i];
        int pos = atomicAdd(&bins[d / BW], 1);
        pairs[pos] = make_int2(s, d);
    }
}

// per-bucket node histogram -> cnt, dis
__global__ void bucket_hist(const int2* __restrict__ pairs, const int* __restrict__ bcursor,
                            int* __restrict__ cnt, float* __restrict__ dis) {
    __shared__ int h[BW];
    int b = blockIdx.x, t = threadIdx.x;
    for (int i = t; i < BW; i += 256) h[i] = 0;
    __syncthreads();
    int base = b * CAP, n = bcursor[b] - base;
    int nb = b * BW;
    for (int i = t; i < n; i += 256)
        atomicAdd(&h[pairs[base + i].y - nb], 1);
    __syncthreads();
    for (int i = t; i < BW; i += 256) {
        int c = h[i];
        cnt[nb + i] = c;
        dis[nb + i] = rsqrtf((float)c + 1.0f);
    }
}

// per-block sums of cnt (block b covers nodes [b*BW, b*BW+BW))
__global__ void scan1_kernel(const int* __restrict__ cnt, int* __restrict__ sums) {
    __shared__ int lds[256];
    int b = blockIdx.x, t = threadIdx.x;
    int base = b * BW;
    int s = 0;
    if (t < BW / 4) {
#pragma unroll
        for (int k = 0; k < 4; ++k) s += cnt[base + t * 4 + k];
    }
    lds[t] = s;
    __syncthreads();
    for (int off = 128; off > 0; off >>= 1) {
        if (t < off) lds[t] += lds[t + off];
        __syncthreads();
    }
    if (t == 0) sums[b] = lds[0];
}

// exclusive scan of NB block sums -> offs; seal row_start[N]
__global__ void scan2_kernel(const int* __restrict__ sums, int* __restrict__ offs,
                             int* __restrict__ row_start) {
    __shared__ int lds[256];
    int t = threadIdx.x;  // 256 threads
    int own = (t < NB) ? sums[t] : 0;
    lds[t] = own;
    __syncthreads();
    for (int off = 1; off < 256; off <<= 1) {
        int v = (t >= off) ? lds[t - off] : 0;
        __syncthreads();
        lds[t] += v;
        __syncthreads();
    }
    if (t < NB) offs[t] = lds[t] - own;  // exclusive
    if (t == 0) row_start[N_NODES] = N_EDGES;
}

// within-block exclusive scan -> row_start
__global__ void scan3_kernel(const int* __restrict__ cnt, const int* __restrict__ offs,
                             int* __restrict__ row_start) {
    __shared__ int lds[256];
    int b = blockIdx.x, t = threadIdx.x;
    int base = b * BW;
    int local[4];
    int s = 0;
    if (t < BW / 4) {
#pragma unroll
        for (int k = 0; k < 4; ++k) { local[k] = cnt[base + t * 4 + k]; s += local[k]; }
    }
    lds[t] = s;
    __syncthreads();
    for (int off = 1; off < 256; off <<= 1) {
        int v = (t >= off) ? lds[t - off] : 0;
        __syncthreads();
        lds[t] += v;
        __syncthreads();
    }
    if (t < BW / 4) {
        int pre = lds[t] - s + offs[b];
#pragma unroll
        for (int k = 0; k < 4; ++k) {
            row_start[base + t * 4 + k] = pre;
            pre += local[k];
        }
    }
}

// per-bucket CSR fill with LDS cursors; csr writes stay XCD-L2-local
__global__ void bucket_fill(const int2* __restrict__ pairs, const int* __restrict__ bcursor,
                            const int* __restrict__ row_start, int* __restrict__ csr) {
    __shared__ int cur[BW];
    int b = blockIdx.x, t = threadIdx.x;  // 512 threads
    int nb = b * BW;
    for (int i = t; i < BW; i += 512) cur[i] = row_start[nb + i];
    __syncthreads();
    int base = b * CAP, n = bcursor[b] - base;
    for (int i = t; i < n; i += 512) {
        int2 p = pairs[base + i];
        int pos = atomicAdd(&cur[p.y - nb], 1);
        csr[pos] = p.x;
    }
}

// ---------- compute ----------

// Y[r][c] = sum_k X[r][k] * W[k][c] (+ bias[c] if bias != nullptr), nrows rows
__global__ void gemm_kernel(const float* __restrict__ X, const float* __restrict__ W,
                            const float* __restrict__ bias, float* __restrict__ Y,
                            int nrows) {
    __shared__ float Ws[64][64];
    for (int i = threadIdx.x; i < 64 * 64; i += 256)
        Ws[i >> 6][i & 63] = W[i];
    __syncthreads();
    int c  = threadIdx.x & 63;
    int rl = threadIdx.x >> 6;  // 0..3
    int r  = blockIdx.x * 4 + rl;
    if (r < nrows) {
        const float* xr = X + (size_t)r * D;
        float acc = bias ? bias[c] : 0.0f;
#pragma unroll
        for (int k = 0; k < 64; ++k)
            acc = fmaf(xr[k], Ws[k][c], acc);
        Y[(size_t)r * D + c] = acc;
    }
}

// one wave per dst node: gather in-edges, fuse self-loop + bias + relu
__global__ void gather_kernel(const float* __restrict__ H, const int* __restrict__ csr,
                              const int* __restrict__ row_start, const float* __restrict__ dis,
                              const float* __restrict__ bias, float* __restrict__ Bout,
                              int do_relu) {
    int v = (blockIdx.x * blockDim.x + threadIdx.x) >> 6;
    int lane = threadIdx.x & 63;
    if (v >= N_NODES) return;
    int base = row_start[v];
    int n = row_start[v + 1] - base;
    float disv = dis[v];
    float acc = fmaf(H[(size_t)v * D + lane], disv * disv, bias[lane]);
    for (int c = 0; c < n; c += 64) {
        int m = min(64, n - c);
        int sl = 0; float dl = 0.0f;
        if (lane < m) { sl = csr[base + c + lane]; dl = dis[sl]; }
        for (int j = 0; j < m; ++j) {
            int s = __shfl(sl, j);
            float nrm = __shfl(dl, j) * disv;
            acc = fmaf(H[(size_t)s * D + lane], nrm, acc);
        }
    }
    if (do_relu) acc = fmaxf(acc, 0.0f);
    Bout[(size_t)v * D + lane] = acc;
}

// one block per graph: mean over contiguous node segment [ptr[g], ptr[g+1])
__global__ void pool_kernel(const float* __restrict__ H, const int* __restrict__ ptr,
                            float* __restrict__ out) {
    int g = blockIdx.x;
    int start = ptr[g], end = ptr[g + 1];
    int lane  = threadIdx.x & 63;
    int chunk = threadIdx.x >> 6;  // 0..3
    float acc = 0.0f;
    for (int r = start + chunk; r < end; r += 4)
        acc += H[(size_t)r * D + lane];
    __shared__ float tmp[4][64];
    tmp[chunk][lane] = acc;
    __syncthreads();
    if (threadIdx.x < 64) {
        float s = tmp[0][lane] + tmp[1][lane] + tmp[2][lane] + tmp[3][lane];
        out[g * D + lane] = s / (float)(end - start);
    }
}

extern "C" void kernel_launch(void* const* d_in, const int* in_sizes, int n_in,
                              void* d_out, int out_size, void* d_ws, size_t ws_size,
                              hipStream_t stream) {
    const float* x   = (const float*)d_in[0];
    const int*   ei  = (const int*)d_in[1];
    const int*   src = ei;
    const int*   dst = ei + N_EDGES;
    const int*   ptr = (const int*)d_in[2];
    const float* W1  = (const float*)d_in[3];
    const float* b1  = (const float*)d_in[4];
    const float* W2  = (const float*)d_in[5];
    const float* b2  = (const float*)d_in[6];
    const float* Wf  = (const float*)d_in[7];
    const float* bfp = (const float*)d_in[8];
    float* out = (float*)d_out;

    // workspace layout (4-byte units)
    int*   cnt       = (int*)d_ws;                  // 100352
    int*   row_start = cnt + 100352;                // 100352 (N+1 used)
    int*   sums      = row_start + 100352;          // 256
    int*   offs      = sums + 256;                  // 256
    int*   bcursor   = offs + 256;                  // 256
    float* P         = (float*)(bcursor + 256);     // 8192 (125*64 used)
    float* dis       = P + 8192;                    // 100352
    int*   csr       = (int*)(dis + 100352);        // 3200000
    float* A         = (float*)(csr + 3200000);     // 6400000
    float* B         = A + (size_t)N_NODES * D;     // 6400000
    int2*  pairs     = (int2*)A;                    // NB*CAP = 4.096M int2, aliases A+B

    // --- CSR build ---
    init_bcursor<<<1, 256, 0, stream>>>(bcursor);
    bucket_scatter<<<NB, 256, 0, stream>>>(src, dst, bcursor, pairs);
    bucket_hist<<<NB, 256, 0, stream>>>(pairs, bcursor, cnt, dis);
    scan1_kernel<<<NB, 256, 0, stream>>>(cnt, sums);
    scan2_kernel<<<1, 256, 0, stream>>>(sums, offs, row_start);
    scan3_kernel<<<NB, 256, 0, stream>>>(cnt, offs, row_start);
    bucket_fill<<<NB, 512, 0, stream>>>(pairs, bcursor, row_start, csr);

    const int grid4 = (N_NODES + 3) / 4;

    // layer 1: A = x @ W1 ; B = relu(gather(A) + A*dis^2 + b1)
    gemm_kernel<<<grid4, 256, 0, stream>>>(x, W1, nullptr, A, N_NODES);
    gather_kernel<<<grid4, 256, 0, stream>>>(A, csr, row_start, dis, b1, B, 1);

    // layer 2
    gemm_kernel<<<grid4, 256, 0, stream>>>(B, W2, nullptr, A, N_NODES);
    gather_kernel<<<grid4, 256, 0, stream>>>(A, csr, row_start, dis, b2, B, 1);

    // head: pool first (mean commutes with linear head), then tiny GEMM
    pool_kernel<<<N_GRAPHS, 256, 0, stream>>>(B, ptr, P);
    gemm_kernel<<<(N_GRAPHS + 3) / 4, 256, 0, stream>>>(P, Wf, bfp, out, N_GRAPHS);
}